// Round 15
// baseline (1773.792 us; speedup 1.0000x reference)
//
#include <hip/hip_runtime.h>

// Problem dims
#define NB    2
#define SEQ   512
#define NL    12
#define DIM   1024
#define NH    16
#define HD    64
#define DFF   4096
#define VOCAB 2048
#define CHD   7

typedef __attribute__((ext_vector_type(4))) float f32x4;
typedef __attribute__((ext_vector_type(8))) short s16x8;
typedef __attribute__((ext_vector_type(4))) unsigned short u16x4;
typedef __attribute__((ext_vector_type(8))) unsigned short u16x8;

__device__ __forceinline__ unsigned short f2bf(float f) {
    unsigned u = __builtin_bit_cast(unsigned, f);
    u += 0x7fffu + ((u >> 16) & 1u);           // RNE
    return (unsigned short)(u >> 16);
}

__device__ __forceinline__ void gl2lds16(const void* g, void* l) {
    __builtin_amdgcn_global_load_lds(
        (const __attribute__((address_space(1))) void*)g,
        (__attribute__((address_space(3))) void*)l, 16, 0, 0);
}

// ===========================================================================
// 64x128-tile GEMM (validated shape, 4x applied): BK=64, 256 thr / 4 waves
// (2m x 2n, 32x64 wave-tile), 48 KiB dbuf -> 3 blocks/CU.
// grid (N/128, M/64, wsel*ksplit + kz).
// B select: sBz != 0 -> B0 + wsel*sBz (strided; head GEMM); else ptr-select.
// EPI: 0 = f32 store, 1 = atomicAdd (C idx = wsel*sCz + rowmap),
//      2 = QKV epilogue (wsel 0/1 rope -> q_bf/k_bf; wsel 2 -> vT_bf).
// ===========================================================================
template<int EPI>
__global__ __launch_bounds__(256)
void gemm64(const unsigned short* __restrict__ A,
            const unsigned short* __restrict__ B0,
            const unsigned short* __restrict__ B1,
            const unsigned short* __restrict__ B2,
            float* __restrict__ C, int K, int lda, int ldbT, int ldc,
            int rhi, long sBz, long sCz, int kchunk, int ksplit,
            const float* __restrict__ tc, const float* __restrict__ ts,
            const int* __restrict__ pid, unsigned short* __restrict__ qkv_bf)
{
    __shared__ unsigned short smA[2][4096];   // 64x64  per buf (8 KiB)
    __shared__ unsigned short smB[2][8192];   // 128x64 per buf (16 KiB)  -> 48 KiB

    const int tid = threadIdx.x;
    const int z   = blockIdx.z;
    const int wsel = z / ksplit, kz = z - wsel * ksplit;
    const int m0  = blockIdx.y * 64;
    const int n0  = blockIdx.x * 128;
    const int koff = kz * kchunk;

    const unsigned short* Ap = A + koff;
    const unsigned short* Bp = sBz ? (B0 + (long)wsel * sBz)
                                   : (wsel == 0 ? B0 : (wsel == 1 ? B1 : B2));
    Bp += koff;
    float* Cp = C + (long)wsel * sCz;

    const int w = tid >> 6, l = tid & 63;
    const int lrow = l & 15, lhi = l >> 4;
    const int wm = (w >> 1) * 32, wn = (w & 1) * 64;

    // A staging: 512 chunks, c = w*128 + i*64 + l (i<2)
    int rowA[2], colA[2];
    #pragma unroll
    for (int i = 0; i < 2; ++i) {
        const int c = w * 128 + i * 64 + l;
        rowA[i] = c >> 3;
        colA[i] = (((c & 7) ^ ((c >> 3) & 7)) << 3);
    }
    // B staging: 1024 chunks, c = w*256 + i*64 + l (i<4)
    int rowB[4], colB[4];
    #pragma unroll
    for (int i = 0; i < 4; ++i) {
        const int c = w * 256 + i * 64 + l;
        rowB[i] = c >> 3;
        colB[i] = (((c & 7) ^ ((c >> 3) & 7)) << 3);
    }

    f32x4 acc[2][4] = {};

    auto STAGE = [&](int d, int k0) {
        #pragma unroll
        for (int i = 0; i < 2; ++i)
            gl2lds16(Ap + (long)(m0 + rowA[i]) * lda + k0 + colA[i],
                     &smA[d][0] + (w * 128 + i * 64) * 8);
        #pragma unroll
        for (int i = 0; i < 4; ++i)
            gl2lds16(Bp + (long)(n0 + rowB[i]) * ldbT + k0 + colB[i],
                     &smB[d][0] + (w * 256 + i * 64) * 8);
    };
    auto COMPUTE = [&](int d) {
        const char* Ab = (const char*)&smA[d][0];
        const char* Bb = (const char*)&smB[d][0];
        #pragma unroll
        for (int ks = 0; ks < 2; ++ks) {
            s16x8 af[2], bf[4];
            #pragma unroll
            for (int i = 0; i < 2; ++i) {
                const int r = wm + i * 16 + lrow;
                af[i] = __builtin_bit_cast(s16x8, *reinterpret_cast<const u16x8*>(
                    Ab + r * 128 + (((ks * 4 + lhi) ^ (r & 7)) << 4)));
            }
            #pragma unroll
            for (int j = 0; j < 4; ++j) {
                const int r = wn + j * 16 + lrow;
                bf[j] = __builtin_bit_cast(s16x8, *reinterpret_cast<const u16x8*>(
                    Bb + r * 128 + (((ks * 4 + lhi) ^ (r & 7)) << 4)));
            }
            #pragma unroll
            for (int i = 0; i < 2; ++i)
                #pragma unroll
                for (int j = 0; j < 4; ++j)
                    acc[i][j] = __builtin_amdgcn_mfma_f32_16x16x32_bf16(af[i], bf[j], acc[i][j], 0, 0, 0);
        }
    };

    STAGE(0, 0);
    __syncthreads();
    int cur = 0;
    for (int k0 = 0; k0 < K; k0 += 64) {
        if (k0 + 64 < K) STAGE(cur ^ 1, k0 + 64);
        COMPUTE(cur);
        __syncthreads();
        cur ^= 1;
    }

    if (EPI == 2) {
        // QKV epilogue: rope for q/k (pairs thread-local), transpose for v
        const int h = (n0 + wn) >> 6;
        unsigned short* qb = qkv_bf;                 // [tok][1024] roped
        unsigned short* kb = qkv_bf + 1048576;       // [tok][1024] roped
        unsigned short* vt = qkv_bf + 2097152;       // [(b*16+h)*64+d][512]
        #pragma unroll
        for (int i = 0; i < 2; ++i) {
            const int r0 = m0 + wm + i * 16 + lhi * 4;
            #pragma unroll
            for (int e = 0; e < 4; ++e) {
                const int r = r0 + e;
                if (wsel == 2) {
                    const int bh = (r >> 9) * NH + h, s = r & 511;
                    #pragma unroll
                    for (int j = 0; j < 4; ++j)
                        vt[((long)(bh * 64 + j * 16 + lrow)) * 512 + s] = f2bf(acc[i][j][e]);
                } else {
                    unsigned short* ob = (wsel == 0) ? qb : kb;
                    const int pos = pid[r];
                    const float c0 = tc[pos * 32 + lrow],      s0 = ts[pos * 32 + lrow];
                    const float c1 = tc[pos * 32 + 16 + lrow], s1 = ts[pos * 32 + 16 + lrow];
                    const float a0 = acc[i][0][e], a1 = acc[i][1][e];
                    const float a2 = acc[i][2][e], a3 = acc[i][3][e];
                    const long rb = (long)r * DIM + (n0 + wn) + lrow;
                    ob[rb]      = f2bf(a0 * c0 - a2 * s0);
                    ob[rb + 16] = f2bf(a1 * c1 - a3 * s1);
                    ob[rb + 32] = f2bf(a2 * c0 + a0 * s0);
                    ob[rb + 48] = f2bf(a3 * c1 + a1 * s1);
                }
            }
        }
        return;
    }

    #pragma unroll
    for (int i = 0; i < 2; ++i) {
        const int r0 = m0 + wm + i * 16 + lhi * 4;
        #pragma unroll
        for (int j = 0; j < 4; ++j) {
            const int c = n0 + wn + j * 16 + lrow;
            #pragma unroll
            for (int e = 0; e < 4; ++e) {
                const int r = r0 + e;
                const long idx = (long)(r >> 9) * rhi + (long)(r & 511) * ldc + c;
                if (EPI == 1) atomicAdd(&Cp[idx], acc[i][j][e]);
                else          Cp[idx] = acc[i][j][e];
            }
        }
    }
}

// ===========================================================================
// Fused gate+up+silu GEMM (r12-exact, 64 KiB dbuf): 128x64 tiles of g and u,
// shared A, epilogue gu_bf = bf16(silu(g)*u). grid (DFF/64, M/128) = 512.
// ===========================================================================
__global__ __launch_bounds__(256)
void gemm_gu(const unsigned short* __restrict__ A,
             const unsigned short* __restrict__ Bg0,
             const unsigned short* __restrict__ Bu0,
             unsigned short* __restrict__ GU, int K, int lda, int ldbT)
{
    __shared__ unsigned short sm[32768];     // 64 KiB
    char* const lds = (char*)sm;

    const int tid = threadIdx.x;
    const int m0  = blockIdx.y * 128;
    const int n0  = blockIdx.x * 64;

    const unsigned short* Bg = Bg0 + (long)n0 * ldbT;
    const unsigned short* Bu = Bu0 + (long)n0 * ldbT;

    const int w = tid >> 6, l = tid & 63;
    const int lrow = l & 15, lhi = l >> 4;
    const int wm = (w >> 1) * 64, wn = (w & 1) * 32;

    int rowA[4], colA[4];
    #pragma unroll
    for (int i = 0; i < 4; ++i) {
        const int c = w * 256 + i * 64 + l;
        rowA[i] = c >> 3;
        colA[i] = (((c & 7) ^ ((c >> 3) & 7)) << 3);
    }
    int rowB[2], colB[2];
    #pragma unroll
    for (int i = 0; i < 2; ++i) {
        const int c = w * 128 + i * 64 + l;
        rowB[i] = c >> 3;
        colB[i] = (((c & 7) ^ ((c >> 3) & 7)) << 3);
    }

    f32x4 accg[4][2] = {};
    f32x4 accu[4][2] = {};

    auto STAGE = [&](int d, int k0) {
        char* Ab  = lds + d * 16384;
        char* Bgb = lds + 32768 + d * 8192;
        char* Bub = lds + 49152 + d * 8192;
        #pragma unroll
        for (int i = 0; i < 4; ++i) {
            const int ub = (w * 256 + i * 64) * 16;
            gl2lds16(A + (long)(m0 + rowA[i]) * lda + k0 + colA[i], Ab + ub);
        }
        #pragma unroll
        for (int i = 0; i < 2; ++i) {
            const int ub = (w * 128 + i * 64) * 16;
            gl2lds16(Bg + (long)rowB[i] * ldbT + k0 + colB[i], Bgb + ub);
            gl2lds16(Bu + (long)rowB[i] * ldbT + k0 + colB[i], Bub + ub);
        }
    };
    auto COMPUTE = [&](int d) {
        const char* Ab  = lds + d * 16384;
        const char* Bgb = lds + 32768 + d * 8192;
        const char* Bub = lds + 49152 + d * 8192;
        #pragma unroll
        for (int ks = 0; ks < 2; ++ks) {
            s16x8 af[4], bg[2], bu[2];
            #pragma unroll
            for (int i = 0; i < 4; ++i) {
                const int r = wm + i * 16 + lrow;
                af[i] = __builtin_bit_cast(s16x8, *reinterpret_cast<const u16x8*>(
                    Ab + r * 128 + (((ks * 4 + lhi) ^ (r & 7)) << 4)));
            }
            #pragma unroll
            for (int j = 0; j < 2; ++j) {
                const int r = wn + j * 16 + lrow;
                const int off = r * 128 + (((ks * 4 + lhi) ^ (r & 7)) << 4);
                bg[j] = __builtin_bit_cast(s16x8, *reinterpret_cast<const u16x8*>(Bgb + off));
                bu[j] = __builtin_bit_cast(s16x8, *reinterpret_cast<const u16x8*>(Bub + off));
            }
            #pragma unroll
            for (int i = 0; i < 4; ++i)
                #pragma unroll
                for (int j = 0; j < 2; ++j) {
                    accg[i][j] = __builtin_amdgcn_mfma_f32_16x16x32_bf16(af[i], bg[j], accg[i][j], 0, 0, 0);
                    accu[i][j] = __builtin_amdgcn_mfma_f32_16x16x32_bf16(af[i], bu[j], accu[i][j], 0, 0, 0);
                }
        }
    };

    STAGE(0, 0);
    __syncthreads();
    int cur = 0;
    for (int k0 = 0; k0 < K; k0 += 64) {
        if (k0 + 64 < K) STAGE(cur ^ 1, k0 + 64);
        COMPUTE(cur);
        __syncthreads();
        cur ^= 1;
    }

    #pragma unroll
    for (int i = 0; i < 4; ++i) {
        const int r0 = m0 + wm + i * 16 + lhi * 4;
        #pragma unroll
        for (int j = 0; j < 2; ++j) {
            const int c = n0 + wn + j * 16 + lrow;
            #pragma unroll
            for (int e = 0; e < 4; ++e) {
                const float gx = accg[i][j][e];
                const float ux = accu[i][j][e];
                const float val = gx / (1.0f + __expf(-gx)) * ux;
                GU[(long)(r0 + e) * DFF + c] = f2bf(val);
            }
        }
    }
}

// transpose + f32->bf16 convert: src f32 [R][Cn] -> dst bf16 [Cn][R]
__global__ __launch_bounds__(256)
void tconv_kernel(const float* __restrict__ src, unsigned short* __restrict__ dst,
                  int R, int Cn, long sS, long sD)
{
    __shared__ float tile[64][65];
    const int c0 = blockIdx.x * 64, r0 = blockIdx.y * 64;
    const float* s = src + (long)blockIdx.z * sS;
    unsigned short* d = dst + (long)blockIdx.z * sD;
    const int tid = threadIdx.x;
    #pragma unroll
    for (int it = 0; it < 4; ++it) {
        const int idx = tid + it * 256;
        const int r = idx >> 4, c4 = (idx & 15) * 4;
        f32x4 v = *reinterpret_cast<const f32x4*>(&s[(long)(r0 + r) * Cn + c0 + c4]);
        tile[r][c4] = v[0]; tile[r][c4+1] = v[1]; tile[r][c4+2] = v[2]; tile[r][c4+3] = v[3];
    }
    __syncthreads();
    #pragma unroll
    for (int it = 0; it < 4; ++it) {
        const int idx = tid + it * 256;
        const int n = idx >> 4, r4 = (idx & 15) * 4;
        u16x4 o = { f2bf(tile[r4][n]), f2bf(tile[r4+1][n]),
                    f2bf(tile[r4+2][n]), f2bf(tile[r4+3][n]) };
        *reinterpret_cast<u16x4*>(&d[(long)(c0 + n) * R + r0 + r4]) = o;
    }
}

// rope tables: tc/ts[pos][i], pos<512, i<32
__global__ __launch_bounds__(256)
void ropetab_kernel(float* __restrict__ tc, float* __restrict__ ts)
{
    const int idx = blockIdx.x * 256 + threadIdx.x;   // 16384
    const int pos = idx >> 5, i = idx & 31;
    const float invf = powf(10000.0f, -(float)i * (1.0f / 32.0f));
    const float ang = (float)pos * invf;
    tc[idx] = cosf(ang);
    ts[idx] = sinf(ang);
}

// ---------------------------------------------------------------------------
// Small kernels
// ---------------------------------------------------------------------------
template<bool BF>
__global__ __launch_bounds__(256)
void concat_kernel(const float* __restrict__ a, const float* __restrict__ b,
                   void* __restrict__ outv)
{
    const long i = ((long)blockIdx.x * 256 + threadIdx.x) * 4;
    const int row = (int)(i >> 11), col = (int)(i & 2047);
    const float* src = (col < DIM) ? &a[(long)row * DIM + col]
                                   : &b[(long)row * DIM + col - DIM];
    f32x4 v = *reinterpret_cast<const f32x4*>(src);
    if (BF) {
        u16x4 o = { f2bf(v[0]), f2bf(v[1]), f2bf(v[2]), f2bf(v[3]) };
        *reinterpret_cast<u16x4*>((unsigned short*)outv + i) = o;
    } else {
        *reinterpret_cast<f32x4*>((float*)outv + i) = v;
    }
}

template<bool BF>
__global__ __launch_bounds__(256)
void rms_kernel(const float* __restrict__ in, const float* __restrict__ w,
                void* __restrict__ outv)
{
    __shared__ float red[4];
    const int row = blockIdx.x, tid = threadIdx.x;
    const long base = (long)row * DIM + tid * 4;
    f32x4 v = *reinterpret_cast<const f32x4*>(&in[base]);
    float ss = v[0]*v[0] + v[1]*v[1] + v[2]*v[2] + v[3]*v[3];
    for (int off = 32; off; off >>= 1) ss += __shfl_down(ss, off);
    if ((tid & 63) == 0) red[tid >> 6] = ss;
    __syncthreads();
    float s = red[0] + red[1] + red[2] + red[3];
    float r = 1.0f / sqrtf(s * (1.0f / DIM) + 1e-5f);
    f32x4 wv = *reinterpret_cast<const f32x4*>(&w[tid * 4]);
    f32x4 o = { v[0]*r*wv[0], v[1]*r*wv[1], v[2]*r*wv[2], v[3]*r*wv[3] };
    if (BF) {
        u16x4 ob = { f2bf(o[0]), f2bf(o[1]), f2bf(o[2]), f2bf(o[3]) };
        *reinterpret_cast<u16x4*>((unsigned short*)outv + base) = ob;
    } else {
        *reinterpret_cast<f32x4*>((float*)outv + base) = o;
    }
}

// Flash attention on pre-roped bf16 q/k and pre-transposed bf16 vT.
// QBLK=64, 256 thr / 4 waves, K/V double-buffered via global_load_lds with
// XOR pre-swizzled source. grid (8 qtiles, 32 bh).
__global__ __launch_bounds__(256)
void attn_bf(const unsigned short* __restrict__ qb,
             const unsigned short* __restrict__ kb,
             const unsigned short* __restrict__ vt,
             unsigned short* __restrict__ attv)
{
    __shared__ unsigned short Qs[4096];        // 64x64 swizzled
    __shared__ unsigned short Ps[64][72];
    __shared__ unsigned short Ks[2][4096];
    __shared__ unsigned short Vs[2][4096];
    const int tid = threadIdx.x;
    const int qt = blockIdx.x, bh = blockIdx.y, b = bh >> 4, h = bh & 15;
    const int q0 = qt * 64;
    const int w = tid >> 6, l = tid & 63, lrow = l & 15, lhi = l >> 4;

    int rowS[2], colS[2];
    #pragma unroll
    for (int i = 0; i < 2; ++i) {
        const int c = w * 128 + i * 64 + l;
        rowS[i] = c >> 3;
        colS[i] = (((c & 7) ^ ((c >> 3) & 7)) << 3);   // u16 elems
    }

    auto STAGE64 = [&](const unsigned short* src, long rstride, unsigned short* dst) {
        #pragma unroll
        for (int i = 0; i < 2; ++i)
            gl2lds16(src + (long)rowS[i] * rstride + colS[i],
                     dst + (w * 128 + i * 64) * 8);
    };

    STAGE64(qb + (long)(b * SEQ + q0) * DIM + h * HD, DIM, Qs);

    auto STAGE_KV = [&](int kt, int d) {
        const int t0 = kt * 64;
        STAGE64(kb + (long)(b * SEQ + t0) * DIM + h * HD, DIM, Ks[d]);
        STAGE64(vt + (long)(bh * 64) * 512 + t0, 512, Vs[d]);
    };

    float m_run[4], l_run[4];
    f32x4 o[4] = {};
    #pragma unroll
    for (int j = 0; j < 4; ++j) { m_run[j] = -1e30f; l_run[j] = 0.f; }
    const float scale = 0.125f;

    STAGE_KV(0, 0);
    __syncthreads();

    for (int kt = 0; kt <= qt; ++kt) {
        const int cur = kt & 1;
        const int t0 = kt * 64;
        if (kt < qt) STAGE_KV(kt + 1, cur ^ 1);   // prefetch under compute

        f32x4 s[4] = {};
        __builtin_amdgcn_s_setprio(1);
        #pragma unroll
        for (int ks = 0; ks < 2; ++ks) {
            const int rq = w * 16 + lrow;
            s16x8 aq = __builtin_bit_cast(s16x8, *reinterpret_cast<const u16x8*>(
                (const char*)Qs + rq * 128 + (((ks * 4 + lhi) ^ (rq & 7)) << 4)));
            #pragma unroll
            for (int j = 0; j < 4; ++j) {
                const int rk = j * 16 + lrow;
                s16x8 bk = __builtin_bit_cast(s16x8, *reinterpret_cast<const u16x8*>(
                    (const char*)Ks[cur] + rk * 128 + (((ks * 4 + lhi) ^ (rk & 7)) << 4)));
                s[j] = __builtin_amdgcn_mfma_f32_16x16x32_bf16(aq, bk, s[j], 0, 0, 0);
            }
        }
        __builtin_amdgcn_s_setprio(0);

        float pv[4][4], corr[4];
        #pragma unroll
        for (int j = 0; j < 4; ++j) {
            const int qrow = q0 + w * 16 + lhi * 4 + j;
            float sv[4], mx = -1e30f;
            #pragma unroll
            for (int tcq = 0; tcq < 4; ++tcq) {
                const int tcur = t0 + tcq * 16 + lrow;
                float vvv = s[tcq][j] * scale;
                if (tcur > qrow) vvv = -1e30f;
                sv[tcq] = vvv;
                mx = fmaxf(mx, vvv);
            }
            #pragma unroll
            for (int mk = 1; mk < 16; mk <<= 1) mx = fmaxf(mx, __shfl_xor(mx, mk));
            const float mnew = fmaxf(m_run[j], mx);
            const float c = __expf(m_run[j] - mnew);
            m_run[j] = mnew;
            float rs = 0.f;
            #pragma unroll
            for (int tcq = 0; tcq < 4; ++tcq) {
                float p = __expf(sv[tcq] - mnew);
                pv[tcq][j] = p;
                rs += p;
            }
            #pragma unroll
            for (int mk = 1; mk < 16; mk <<= 1) rs += __shfl_xor(rs, mk);
            l_run[j] = l_run[j] * c + rs;
            corr[j] = c;
        }

        #pragma unroll
        for (int tcq = 0; tcq < 4; ++tcq)
            #pragma unroll
            for (int j = 0; j < 4; ++j)
                Ps[w * 16 + lhi * 4 + j][tcq * 16 + lrow] = f2bf(pv[tcq][j]);

        #pragma unroll
        for (int dn = 0; dn < 4; ++dn)
            #pragma unroll
            for (int j = 0; j < 4; ++j)
                o[dn][j] *= corr[j];
        __builtin_amdgcn_s_setprio(1);
        #pragma unroll
        for (int ks = 0; ks < 2; ++ks) {
            s16x8 ap = __builtin_bit_cast(s16x8,
                *reinterpret_cast<const u16x8*>(&Ps[w * 16 + lrow][ks * 32 + lhi * 8]));
            #pragma unroll
            for (int dn = 0; dn < 4; ++dn) {
                const int rv = dn * 16 + lrow;
                s16x8 bv = __builtin_bit_cast(s16x8, *reinterpret_cast<const u16x8*>(
                    (const char*)Vs[cur] + rv * 128 + (((ks * 4 + lhi) ^ (rv & 7)) << 4)));
                o[dn] = __builtin_amdgcn_mfma_f32_16x16x32_bf16(ap, bv, o[dn], 0, 0, 0);
            }
        }
        __builtin_amdgcn_s_setprio(0);
        __syncthreads();
    }

    #pragma unroll
    for (int dn = 0; dn < 4; ++dn)
        #pragma unroll
        for (int j = 0; j < 4; ++j) {
            const int qrow = q0 + w * 16 + lhi * 4 + j;
            const int d = dn * 16 + lrow;
            const long idx = (((long)(b * SEQ + qrow)) * NH + h) * HD + d;
            attv[idx] = f2bf(o[dn][j] / l_run[j]);
        }
}

// ===========================================================================
// Fallback path kernels (round-2 inline-convert, small workspace)
// ===========================================================================
__device__ __forceinline__ int swz_b(int row, int col_u16) {
    return row * 128 + ((((col_u16 >> 3) ^ (row & 7)) << 4)) + ((col_u16 << 1) & 15);
}

template<bool ATOMIC, bool SILU>
__global__ __launch_bounds__(256)
void gemm128(const float* __restrict__ A, const float* __restrict__ A2,
             const float* __restrict__ B0, const float* __restrict__ B1,
             const float* __restrict__ B2, float* __restrict__ C,
             int K, int lda, int ldb, int ldc,
             int rhi, long sBz, long sCz, int kchunk)
{
    __shared__ unsigned short As[128 * 64];
    __shared__ unsigned short Bs[128 * 64];
    char* const Ab = reinterpret_cast<char*>(As);
    char* const Bb = reinterpret_cast<char*>(Bs);

    const int tid = threadIdx.x;
    const int z   = blockIdx.z;
    const int m0  = blockIdx.y * 128;
    const int n0  = blockIdx.x * 128;

    const float* Bp = sBz ? (B0 + (long)z * sBz) : (z == 0 ? B0 : (z == 1 ? B1 : B2));
    const long koff = (long)z * kchunk;
    const float* Ap  = A + koff;
    const float* A2p = SILU ? (A2 + koff) : nullptr;
    Bp += koff * (long)ldb;
    float* Cp = C + (long)z * sCz;

    const int w = tid >> 6, l = tid & 63;
    const int lrow = l & 15, lhi = l >> 4;
    const int wm = (w >> 1) * 64, wn = (w & 1) * 64;

    f32x4 acc[4][4] = {};

    for (int k0 = 0; k0 < K; k0 += 64) {
        __syncthreads();
        #pragma unroll
        for (int it = 0; it < 8; ++it) {
            const int idx = tid + it * 256;
            const int m = idx >> 4, c4 = (idx & 15) << 2;
            const long ga = (long)(m0 + m) * lda + k0 + c4;
            float4 v = *reinterpret_cast<const float4*>(&Ap[ga]);
            if (SILU) {
                const float4 v2 = *reinterpret_cast<const float4*>(&A2p[ga]);
                v.x = v.x / (1.0f + __expf(-v.x)) * v2.x;
                v.y = v.y / (1.0f + __expf(-v.y)) * v2.y;
                v.z = v.z / (1.0f + __expf(-v.z)) * v2.z;
                v.w = v.w / (1.0f + __expf(-v.w)) * v2.w;
            }
            u16x4 p = { f2bf(v.x), f2bf(v.y), f2bf(v.z), f2bf(v.w) };
            *reinterpret_cast<u16x4*>(Ab + swz_b(m, c4)) = p;
        }
        #pragma unroll
        for (int it = 0; it < 8; ++it) {
            const int idx = tid + it * 256;
            const int n = idx & 127, kq = idx >> 7;
            const long bb = (long)(k0 + kq * 4) * ldb + n0 + n;
            const float b0v = Bp[bb];
            const float b1v = Bp[bb + ldb];
            const float b2v = Bp[bb + 2 * (long)ldb];
            const float b3v = Bp[bb + 3 * (long)ldb];
            u16x4 p = { f2bf(b0v), f2bf(b1v), f2bf(b2v), f2bf(b3v) };
            *reinterpret_cast<u16x4*>(Bb + swz_b(n, kq << 2)) = p;
        }
        __syncthreads();

        #pragma unroll
        for (int ks = 0; ks < 2; ++ks) {
            s16x8 af[4], bfr[4];
            #pragma unroll
            for (int i = 0; i < 4; ++i) {
                const int r = wm + i * 16 + lrow;
                af[i] = __builtin_bit_cast(s16x8,
                    *reinterpret_cast<const u16x8*>(Ab + swz_b(r, ks * 32 + lhi * 8)));
            }
            #pragma unroll
            for (int j = 0; j < 4; ++j) {
                const int r = wn + j * 16 + lrow;
                bfr[j] = __builtin_bit_cast(s16x8,
                    *reinterpret_cast<const u16x8*>(Bb + swz_b(r, ks * 32 + lhi * 8)));
            }
            #pragma unroll
            for (int i = 0; i < 4; ++i)
                #pragma unroll
                for (int j = 0; j < 4; ++j)
                    acc[i][j] = __builtin_amdgcn_mfma_f32_16x16x32_bf16(af[i], bfr[j], acc[i][j], 0, 0, 0);
        }
    }

    #pragma unroll
    for (int i = 0; i < 4; ++i) {
        const int r0 = m0 + wm + i * 16 + lhi * 4;
        #pragma unroll
        for (int j = 0; j < 4; ++j) {
            const int c = n0 + wn + j * 16 + lrow;
            #pragma unroll
            for (int e = 0; e < 4; ++e) {
                const int r = r0 + e;
                const long idx = (long)(r >> 9) * rhi + (long)(r & 511) * ldc + c;
                if (ATOMIC) atomicAdd(&Cp[idx], acc[i][j][e]);
                else        Cp[idx] = acc[i][j][e];
            }
        }
    }
}

__global__ __launch_bounds__(256)
void rope_kernel(float* __restrict__ q, float* __restrict__ k,
                 const int* __restrict__ pid)
{
    const int t = blockIdx.x * 256 + threadIdx.x;
    const int i = t & 31, h = (t >> 5) & 15, s = (t >> 9) & 511, b = t >> 18;
    const int pos = pid[b * SEQ + s];
    const float invf = powf(10000.0f, -(float)i * (1.0f / 32.0f));
    const float ang = (float)pos * invf;
    const float c = cosf(ang), sn = sinf(ang);
    const long base = (((long)(b * SEQ + s)) * NH + h) * HD + i;
    float a1 = q[base], a2 = q[base + 32];
    q[base] = a1 * c - a2 * sn;  q[base + 32] = a2 * c + a1 * sn;
    float b1 = k[base], b2 = k[base + 32];
    k[base] = b1 * c - b2 * sn;  k[base + 32] = b2 * c + b1 * sn;
}

__global__ __launch_bounds__(256)
void transpose_v_kernel(const float* __restrict__ v, float* __restrict__ vT)
{
    __shared__ float tile[64][65];
    const int st = blockIdx.x, bh = blockIdx.y, b = bh >> 4, h = bh & 15;
    const int s0 = st * 64;
    for (int t = threadIdx.x; t < 64 * 16; t += 256) {
        int s = t >> 4, c4 = (t & 15) * 4;
        f32x4 v4 = *reinterpret_cast<const f32x4*>(
            &v[(((long)(b * SEQ + s0 + s)) * NH + h) * HD + c4]);
        tile[s][c4] = v4[0]; tile[s][c4+1] = v4[1]; tile[s][c4+2] = v4[2]; tile[s][c4+3] = v4[3];
    }
    __syncthreads();
    for (int t = threadIdx.x; t < 64 * 16; t += 256) {
        int d = t >> 4, c4 = (t & 15) * 4;
        f32x4 o4 = { tile[c4][d], tile[c4+1][d], tile[c4+2][d], tile[c4+3][d] };
        *reinterpret_cast<f32x4*>(&vT[((long)bh * HD + d) * SEQ + s0 + c4]) = o4;
    }
}

template<bool BF>
__global__ __launch_bounds__(256)
void attn_kernel(const float* __restrict__ q, const float* __restrict__ k,
                 const float* __restrict__ vT, void* __restrict__ attv)
{
    __shared__ unsigned short Qs[64][72];
    __shared__ unsigned short Ks[64][72];
    __shared__ unsigned short Ps[64][72];
    __shared__ unsigned short Vs[64][72];
    const int tid = threadIdx.x;
    const int qt = blockIdx.x, bh = blockIdx.y, b = bh >> 4, h = bh & 15;
    const int q0 = qt * 64;
    const int w = tid >> 6, l = tid & 63, lrow = l & 15, lhi = l >> 4;

    for (int t = tid; t < 64 * 16; t += 256) {
        int r = t >> 4, c4 = (t & 15) * 4;
        f32x4 v4 = *reinterpret_cast<const f32x4*>(
            &q[(((long)(b * SEQ + q0 + r)) * NH + h) * HD + c4]);
        u16x4 p = { f2bf(v4[0]), f2bf(v4[1]), f2bf(v4[2]), f2bf(v4[3]) };
        *reinterpret_cast<u16x4*>(&Qs[r][c4]) = p;
    }

    float m_run[4], l_run[4];
    f32x4 o[4] = {};
    #pragma unroll
    for (int j = 0; j < 4; ++j) { m_run[j] = -1e30f; l_run[j] = 0.f; }
    const float scale = 0.125f;

    for (int kt = 0; kt <= qt; ++kt) {
        const int t0 = kt * 64;
        __syncthreads();
        for (int t = tid; t < 64 * 16; t += 256) {
            int r = t >> 4, c4 = (t & 15) * 4;
            f32x4 v4 = *reinterpret_cast<const f32x4*>(
                &k[(((long)(b * SEQ + t0 + r)) * NH + h) * HD + c4]);
            u16x4 p = { f2bf(v4[0]), f2bf(v4[1]), f2bf(v4[2]), f2bf(v4[3]) };
            *reinterpret_cast<u16x4*>(&Ks[r][c4]) = p;
        }
        for (int t = tid; t < 64 * 16; t += 256) {
            int d = t >> 4, c4 = (t & 15) * 4;
            f32x4 v4 = *reinterpret_cast<const f32x4*>(
                &vT[((long)bh * HD + d) * SEQ + t0 + c4]);
            u16x4 p = { f2bf(v4[0]), f2bf(v4[1]), f2bf(v4[2]), f2bf(v4[3]) };
            *reinterpret_cast<u16x4*>(&Vs[d][c4]) = p;
        }
        __syncthreads();

        f32x4 s[4] = {};
        #pragma unroll
        for (int ks = 0; ks < 2; ++ks) {
            s16x8 aq = __builtin_bit_cast(s16x8,
                *reinterpret_cast<const u16x8*>(&Qs[w * 16 + lrow][ks * 32 + lhi * 8]));
            #pragma unroll
            for (int j = 0; j < 4; ++j) {
                s16x8 bk = __builtin_bit_cast(s16x8,
                    *reinterpret_cast<const u16x8*>(&Ks[j * 16 + lrow][ks * 32 + lhi * 8]));
                s[j] = __builtin_amdgcn_mfma_f32_16x16x32_bf16(aq, bk, s[j], 0, 0, 0);
            }
        }

        float pv[4][4], corr[4];
        #pragma unroll
        for (int j = 0; j < 4; ++j) {
            const int qrow = q0 + w * 16 + lhi * 4 + j;
            float sv[4], mx = -1e30f;
            #pragma unroll
            for (int tcq = 0; tcq < 4; ++tcq) {
                const int tcur = t0 + tcq * 16 + lrow;
                float vvv = s[tcq][j] * scale;
                if (tcur > qrow) vvv = -1e30f;
                sv[tcq] = vvv;
                mx = fmaxf(mx, vvv);
            }
            #pragma unroll
            for (int mk = 1; mk < 16; mk <<= 1) mx = fmaxf(mx, __shfl_xor(mx, mk));
            const float mnew = fmaxf(m_run[j], mx);
            const float c = __expf(m_run[j] - mnew);
            m_run[j] = mnew;
            float rs = 0.f;
            #pragma unroll
            for (int tcq = 0; tcq < 4; ++tcq) {
                float p = __expf(sv[tcq] - mnew);
                pv[tcq][j] = p;
                rs += p;
            }
            #pragma unroll
            for (int mk = 1; mk < 16; mk <<= 1) rs += __shfl_xor(rs, mk);
            l_run[j] = l_run[j] * c + rs;
            corr[j] = c;
        }

        #pragma unroll
        for (int tcq = 0; tcq < 4; ++tcq)
            #pragma unroll
            for (int j = 0; j < 4; ++j)
                Ps[w * 16 + lhi * 4 + j][tcq * 16 + lrow] = f2bf(pv[tcq][j]);

        #pragma unroll
        for (int dn = 0; dn < 4; ++dn)
            #pragma unroll
            for (int j = 0; j < 4; ++j)
                o[dn][j] *= corr[j];
        #pragma unroll
        for (int ks = 0; ks < 2; ++ks) {
            s16x8 ap = __builtin_bit_cast(s16x8,
                *reinterpret_cast<const u16x8*>(&Ps[w * 16 + lrow][ks * 32 + lhi * 8]));
            #pragma unroll
            for (int dn = 0; dn < 4; ++dn) {
                s16x8 bv = __builtin_bit_cast(s16x8,
                    *reinterpret_cast<const u16x8*>(&Vs[dn * 16 + lrow][ks * 32 + lhi * 8]));
                o[dn] = __builtin_amdgcn_mfma_f32_16x16x32_bf16(ap, bv, o[dn], 0, 0, 0);
            }
        }
    }

    #pragma unroll
    for (int dn = 0; dn < 4; ++dn)
        #pragma unroll
        for (int j = 0; j < 4; ++j) {
            const int qrow = q0 + w * 16 + lhi * 4 + j;
            const int d = dn * 16 + lrow;
            const long idx = (((long)(b * SEQ + qrow)) * NH + h) * HD + d;
            const float val = o[dn][j] / l_run[j];
            if (BF) ((unsigned short*)attv)[idx] = f2bf(val);
            else    ((float*)attv)[idx] = val;
        }
}

// silu(g)*u -> bf16 (fallback path)
__global__ __launch_bounds__(256)
void silu_bf_kernel(const float* __restrict__ g, const float* __restrict__ u,
                    unsigned short* __restrict__ o)
{
    const long i = ((long)blockIdx.x * 256 + threadIdx.x) * 4;
    f32x4 gv = *reinterpret_cast<const f32x4*>(&g[i]);
    f32x4 uv = *reinterpret_cast<const f32x4*>(&u[i]);
    u16x4 r;
    #pragma unroll
    for (int e = 0; e < 4; ++e) {
        float gx = gv[e];
        r[e] = f2bf(gx / (1.0f + __expf(-gx)) * uv[e]);
    }
    *reinterpret_cast<u16x4*>(&o[i]) = r;
}

// ---------------------------------------------------------------------------
extern "C" void kernel_launch(void* const* d_in, const int* in_sizes, int n_in,
                              void* d_out, int out_size, void* d_ws, size_t ws_size,
                              hipStream_t stream)
{
    const float* f2   = (const float*)d_in[0];
    const float* ph   = (const float*)d_in[1];
    const float* wbr  = (const float*)d_in[3];
    const float* ln1  = (const float*)d_in[4];
    const float* wq   = (const float*)d_in[5];
    const float* wk   = (const float*)d_in[6];
    const float* wv   = (const float*)d_in[7];
    const float* wo   = (const float*)d_in[8];
    const float* ln2  = (const float*)d_in[9];
    const float* wg   = (const float*)d_in[10];
    const float* wu   = (const float*)d_in[11];
    const float* wd   = (const float*)d_in[12];
    const float* nw   = (const float*)d_in[13];
    const float* wout = (const float*)d_in[14];
    const int*   pid  = (const int*)d_in[15];
    float* out = (float*)d_out;

    const long M1 = 1048576;
    dim3 blk(256);

    const size_t NEED = (size_t)122 * M1 * 4;   // ~488 MiB
    if (ws_size >= NEED) {
        // =============== big-workspace bf16 path ===============
        float* ws = (float*)d_ws;
        float* h    = ws;                        // 1M f32
        float* tcos = ws + 1 * M1;               // 16384 f32
        float* tsin = ws + 1 * M1 + 16384;
        unsigned short* xcat_bf = (unsigned short*)(ws + 2 * M1);   // 2M u16
        unsigned short* x_bf    = (unsigned short*)(ws + 3 * M1);   // 1M u16
        unsigned short* att_bf  = (unsigned short*)(ws + 3 * M1 + 524288);
        unsigned short* gu_bf   = (unsigned short*)(ws + 4 * M1);   // 4M u16
        unsigned short* qkv_bf  = (unsigned short*)(ws + 6 * M1);   // 3M u16 (q,k,vT)
        unsigned short* wT      = (unsigned short*)(ws + 17 * M1);
        unsigned short* wbrT  = wT;                  // 2M elts
        unsigned short* wqT   = wbrT + 2 * M1;       // 12M
        unsigned short* wkT   = wqT + 12 * M1;
        unsigned short* wvT   = wkT + 12 * M1;
        unsigned short* woT   = wvT + 12 * M1;
        unsigned short* wgT   = woT + 12 * M1;       // 48M
        unsigned short* wuT   = wgT + 48 * M1;
        unsigned short* wdT   = wuT + 48 * M1;
        unsigned short* woutT = wdT + 48 * M1;       // 14.34M

        // prepass: rope tables + weight convert/transpose
        ropetab_kernel<<<64, blk, 0, stream>>>(tcos, tsin);
        tconv_kernel<<<dim3(16, 32, 1), blk, 0, stream>>>(wbr, wbrT, 2048, 1024, 0, 0);
        tconv_kernel<<<dim3(16, 16, NL), blk, 0, stream>>>(wq, wqT, 1024, 1024, M1, M1);
        tconv_kernel<<<dim3(16, 16, NL), blk, 0, stream>>>(wk, wkT, 1024, 1024, M1, M1);
        tconv_kernel<<<dim3(16, 16, NL), blk, 0, stream>>>(wv, wvT, 1024, 1024, M1, M1);
        tconv_kernel<<<dim3(16, 16, NL), blk, 0, stream>>>(wo, woT, 1024, 1024, M1, M1);
        tconv_kernel<<<dim3(64, 16, NL), blk, 0, stream>>>(wg, wgT, 1024, 4096, 4 * M1, 4 * M1);
        tconv_kernel<<<dim3(64, 16, NL), blk, 0, stream>>>(wu, wuT, 1024, 4096, 4 * M1, 4 * M1);
        tconv_kernel<<<dim3(16, 64, NL), blk, 0, stream>>>(wd, wdT, 4096, 1024, 4 * M1, 4 * M1);
        tconv_kernel<<<dim3(32, 16, CHD), blk, 0, stream>>>(wout, woutT, 1024, 2048, 2 * M1, 2 * M1);

        concat_kernel<true><<<2048, blk, 0, stream>>>(f2, ph, xcat_bf);
        hipMemsetAsync(h, 0, M1 * 4, stream);
        // bridge: 64x128 tiles, K=2048 split 4 -> 512 blocks (8 K-steps each)
        gemm64<1><<<dim3(8, 16, 4), blk, 0, stream>>>(
            xcat_bf, wbrT, wbrT, wbrT, h, 512, 2048, 2048, 1024,
            512 * 1024, 0, 0, 512, 4, nullptr, nullptr, nullptr, nullptr);

        for (int i = 0; i < NL; ++i) {
            rms_kernel<true><<<1024, blk, 0, stream>>>(h, ln1 + (long)i * DIM, x_bf);
            // QKV: 64x128 tiles -> 384 blocks, fused rope/V-T epilogue
            gemm64<2><<<dim3(8, 16, 3), blk, 0, stream>>>(
                x_bf, wqT + (long)i * M1, wkT + (long)i * M1, wvT + (long)i * M1,
                nullptr, 1024, 1024, 1024, 0, 0, 0, 0, 0, 1,
                tcos, tsin, pid, qkv_bf);
            attn_bf<<<dim3(8, 32), blk, 0, stream>>>(
                qkv_bf, qkv_bf + M1, qkv_bf + 2 * M1, att_bf);
            // wo: 64x128 tiles, K=1024 split 4 -> 512 blocks, atomic into live h
            gemm64<1><<<dim3(8, 16, 4), blk, 0, stream>>>(
                att_bf, woT + (long)i * M1, woT + (long)i * M1, woT + (long)i * M1, h,
                256, 1024, 1024, 1024, 512 * 1024, 0, 0, 256, 4,
                nullptr, nullptr, nullptr, nullptr);

            rms_kernel<true><<<1024, blk, 0, stream>>>(h, ln2 + (long)i * DIM, x_bf);
            // fused gate+up+silu (r12-exact): 128x64 tiles, 512 blocks
            gemm_gu<<<dim3(64, 8), blk, 0, stream>>>(
                x_bf, wgT + (long)i * 4 * M1, wuT + (long)i * 4 * M1, gu_bf, 1024, 1024, 1024);
            // down: 64x128 tiles, K=4096 split 4 -> 512 blocks, K=1024/block
            gemm64<1><<<dim3(8, 16, 4), blk, 0, stream>>>(
                gu_bf, wdT + (long)i * 4 * M1, wdT + (long)i * 4 * M1, wdT + (long)i * 4 * M1, h,
                1024, 4096, 4096, 1024, 512 * 1024, 0, 0, 1024, 4,
                nullptr, nullptr, nullptr, nullptr);
        }

        rms_kernel<true><<<1024, blk, 0, stream>>>(h, nw, x_bf);
        // head: 64x128 tiles, strided-B (7 heads) -> grid (16,16,7) = 1792 blocks
        gemm64<0><<<dim3(16, 16, CHD), blk, 0, stream>>>(
            x_bf, woutT, nullptr, nullptr, out,
            1024, 1024, 1024, 2048, CHD * 512 * 2048, 2 * M1, (long)512 * 2048, 0, 1,
            nullptr, nullptr, nullptr, nullptr);
        return;
    }

    // =============== fallback: round-2 inline-convert path ===============
    float* ws = (float*)d_ws;
    float* xcat = ws;                  // 2M
    float* h    = ws + 2 * M1;
    float* x    = ws + 3 * M1;
    float* q    = ws + 4 * M1;
    float* kb   = ws + 5 * M1;
    float* v    = ws + 6 * M1;
    float* vT   = ws + 7 * M1;
    float* att  = ws + 8 * M1;
    float* g    = ws + 9 * M1;         // 4M
    float* u    = ws + 13 * M1;        // 4M

    concat_kernel<false><<<2048, blk, 0, stream>>>(f2, ph, xcat);
    gemm128<false, false><<<dim3(8, 8, 1), blk, 0, stream>>>(
        xcat, nullptr, wbr, wbr, wbr, h, 2048, 2048, DIM, DIM, 512 * DIM, 0, 0, 0);

    for (int i = 0; i < NL; ++i) {
        rms_kernel<false><<<1024, blk, 0, stream>>>(h, ln1 + (long)i * DIM, x);
        gemm128<false, false><<<dim3(8, 8, 3), blk, 0, stream>>>(
            x, nullptr, wq + (long)i * M1, wk + (long)i * M1, wv + (long)i * M1, q,
            1024, DIM, DIM, DIM, 512 * DIM, 0, M1, 0);
        rope_kernel<<<2048, blk, 0, stream>>>(q, kb, pid);
        transpose_v_kernel<<<dim3(8, 32), blk, 0, stream>>>(v, vT);
        attn_kernel<false><<<dim3(8, 32), blk, 0, stream>>>(q, kb, vT, att);
        gemm128<true, false><<<dim3(8, 8, 2), blk, 0, stream>>>(
            att, nullptr, wo + (long)i * M1, wo + (long)i * M1, wo + (long)i * M1, h,
            512, DIM, DIM, DIM, 512 * DIM, 0, 0, 512);

        rms_kernel<false><<<1024, blk, 0, stream>>>(h, ln2 + (long)i * DIM, x);
        gemm128<false, false><<<dim3(32, 8, 1), blk, 0, stream>>>(
            x, nullptr, wg + (long)i * 4 * M1, wg + (long)i * 4 * M1, wg + (long)i * 4 * M1, g,
            1024, DIM, DFF, DFF, 512 * DFF, 0, 0, 0);
        gemm128<false, false><<<dim3(32, 8, 1), blk, 0, stream>>>(
            x, nullptr, wu + (long)i * 4 * M1, wu + (long)i * 4 * M1, wu + (long)i * 4 * M1, u,
            1024, DIM, DFF, DFF, 512 * DFF, 0, 0, 0);
        gemm128<true, true><<<dim3(8, 8, 4), blk, 0, stream>>>(
            g, u, wd + (long)i * 4 * M1, wd + (long)i * 4 * M1, wd + (long)i * 4 * M1, h,
            1024, DFF, DIM, DIM, 512 * DIM, 0, 0, 1024);
    }

    rms_kernel<false><<<1024, blk, 0, stream>>>(h, nw, x);
    gemm128<false, false><<<dim3(16, 8, CHD), blk, 0, stream>>>(
        x, nullptr, wout, wout, wout, out,
        1024, DIM, VOCAB, VOCAB, CHD * 512 * VOCAB, (long)DIM * VOCAB, (long)512 * VOCAB, 0);
}

// Round 16
// 1754.749 us; speedup vs baseline: 1.0109x; 1.0109x over previous
//
#include <hip/hip_runtime.h>

// Problem dims
#define NB    2
#define SEQ   512
#define NL    12
#define DIM   1024
#define NH    16
#define HD    64
#define DFF   4096
#define VOCAB 2048
#define CHD   7

typedef __attribute__((ext_vector_type(4))) float f32x4;
typedef __attribute__((ext_vector_type(8))) short s16x8;
typedef __attribute__((ext_vector_type(4))) unsigned short u16x4;
typedef __attribute__((ext_vector_type(8))) unsigned short u16x8;

__device__ __forceinline__ unsigned short f2bf(float f) {
    unsigned u = __builtin_bit_cast(unsigned, f);
    u += 0x7fffu + ((u >> 16) & 1u);           // RNE
    return (unsigned short)(u >> 16);
}

__device__ __forceinline__ void gl2lds16(const void* g, void* l) {
    __builtin_amdgcn_global_load_lds(
        (const __attribute__((address_space(1))) void*)g,
        (__attribute__((address_space(3))) void*)l, 16, 0, 0);
}

// ===========================================================================
// bf16 GEMM, 128x128 tile (head GEMM: M=1024, N=2048x7): BK=64, 256 thr /
// 4 waves / 4x4 frags, 64 KiB dbuf LDS, global_load_lds w16, XOR-swizzled.
// B: sBz strided select. EPI: 0 = f32 store, 1 = atomicAdd.
// ===========================================================================
template<int EPI>
__global__ __launch_bounds__(256)
void gemm_bf(const unsigned short* __restrict__ A,
             const unsigned short* __restrict__ B0,
             const unsigned short* __restrict__ B1,
             const unsigned short* __restrict__ B2,
             float* __restrict__ C, int K, int lda, int ldbT, int ldc,
             int rhi, long sBz, long sCz, int kchunk, int ksplit)
{
    __shared__ unsigned short sm[4][8192];   // 64 KiB

    const int tid = threadIdx.x;
    const int z   = blockIdx.z;
    const int wsel = z / ksplit, kz = z - wsel * ksplit;
    const int m0  = blockIdx.y * 128;
    const int n0  = blockIdx.x * 128;
    const int koff = kz * kchunk;

    const unsigned short* Ap = A + koff;
    const unsigned short* Bp = sBz ? (B0 + (long)wsel * sBz)
                                   : (wsel == 0 ? B0 : (wsel == 1 ? B1 : B2));
    Bp += koff;
    float* Cp = C + (long)wsel * sCz;

    const int w = tid >> 6, l = tid & 63;
    const int lrow = l & 15, lhi = l >> 4;
    const int wm = (w >> 1) * 64, wn = (w & 1) * 64;

    int rowS[4], colS[4];
    #pragma unroll
    for (int i = 0; i < 4; ++i) {
        const int c = w * 256 + i * 64 + l;
        rowS[i] = c >> 3;
        colS[i] = (((c & 7) ^ ((c >> 3) & 7)) << 3);   // u16 elements
    }

    f32x4 acc[4][4] = {};

    auto STAGE = [&](int d, int k0) {
        unsigned short* Ab = &sm[d * 2][0];
        unsigned short* Bb = &sm[d * 2 + 1][0];
        #pragma unroll
        for (int i = 0; i < 4; ++i) {
            const int ub = (w * 256 + i * 64) * 8;     // wave-uniform LDS base (u16)
            gl2lds16(Ap + (long)(m0 + rowS[i]) * lda + k0 + colS[i], Ab + ub);
            gl2lds16(Bp + (long)(n0 + rowS[i]) * ldbT + k0 + colS[i], Bb + ub);
        }
    };
    auto COMPUTE = [&](int d) {
        const char* Ab = (const char*)&sm[d * 2][0];
        const char* Bb = (const char*)&sm[d * 2 + 1][0];
        #pragma unroll
        for (int ks = 0; ks < 2; ++ks) {
            s16x8 af[4], bf[4];
            #pragma unroll
            for (int i = 0; i < 4; ++i) {
                const int r = wm + i * 16 + lrow;
                af[i] = __builtin_bit_cast(s16x8, *reinterpret_cast<const u16x8*>(
                    Ab + r * 128 + (((ks * 4 + lhi) ^ (r & 7)) << 4)));
            }
            #pragma unroll
            for (int j = 0; j < 4; ++j) {
                const int r = wn + j * 16 + lrow;
                bf[j] = __builtin_bit_cast(s16x8, *reinterpret_cast<const u16x8*>(
                    Bb + r * 128 + (((ks * 4 + lhi) ^ (r & 7)) << 4)));
            }
            #pragma unroll
            for (int i = 0; i < 4; ++i)
                #pragma unroll
                for (int j = 0; j < 4; ++j)
                    acc[i][j] = __builtin_amdgcn_mfma_f32_16x16x32_bf16(af[i], bf[j], acc[i][j], 0, 0, 0);
        }
    };

    STAGE(0, 0);
    __syncthreads();
    int cur = 0;
    for (int k0 = 0; k0 < K; k0 += 64) {
        if (k0 + 64 < K) STAGE(cur ^ 1, k0 + 64);
        COMPUTE(cur);
        __syncthreads();
        cur ^= 1;
    }

    #pragma unroll
    for (int i = 0; i < 4; ++i) {
        const int r0 = m0 + wm + i * 16 + lhi * 4;
        #pragma unroll
        for (int j = 0; j < 4; ++j) {
            const int c = n0 + wn + j * 16 + lrow;
            #pragma unroll
            for (int e = 0; e < 4; ++e) {
                const int r = r0 + e;
                const long idx = (long)(r >> 9) * rhi + (long)(r & 511) * ldc + c;
                if (EPI == 1) atomicAdd(&Cp[idx], acc[i][j][e]);
                else          Cp[idx] = acc[i][j][e];
            }
        }
    }
}

// ===========================================================================
// 64x128-tile GEMM (validated: QKV/wo/down/bridge): BK=64, 256 thr / 4 waves
// (2m x 2n, 32x64 wave-tile), 48 KiB dbuf -> 3 blocks/CU.
// grid (N/128, M/64, wsel*ksplit + kz). B via pointer-select.
// EPI: 0 = f32 store, 1 = atomicAdd (C += wsel*sCz),
//      2 = QKV epilogue (wsel 0/1 rope -> q_bf/k_bf; wsel 2 -> vT_bf).
// ===========================================================================
template<int EPI>
__global__ __launch_bounds__(256)
void gemm64(const unsigned short* __restrict__ A,
            const unsigned short* __restrict__ B0,
            const unsigned short* __restrict__ B1,
            const unsigned short* __restrict__ B2,
            float* __restrict__ C, int K, int lda, int ldbT, int ldc,
            int rhi, long sCz, int kchunk, int ksplit,
            const float* __restrict__ tc, const float* __restrict__ ts,
            const int* __restrict__ pid, unsigned short* __restrict__ qkv_bf)
{
    __shared__ unsigned short smA[2][4096];   // 64x64  per buf (8 KiB)
    __shared__ unsigned short smB[2][8192];   // 128x64 per buf (16 KiB)  -> 48 KiB

    const int tid = threadIdx.x;
    const int z   = blockIdx.z;
    const int wsel = z / ksplit, kz = z - wsel * ksplit;
    const int m0  = blockIdx.y * 64;
    const int n0  = blockIdx.x * 128;
    const int koff = kz * kchunk;

    const unsigned short* Ap = A + koff;
    const unsigned short* Bp = (wsel == 0 ? B0 : (wsel == 1 ? B1 : B2));
    Bp += koff;
    float* Cp = C + (long)wsel * sCz;

    const int w = tid >> 6, l = tid & 63;
    const int lrow = l & 15, lhi = l >> 4;
    const int wm = (w >> 1) * 32, wn = (w & 1) * 64;

    int rowA[2], colA[2];
    #pragma unroll
    for (int i = 0; i < 2; ++i) {
        const int c = w * 128 + i * 64 + l;
        rowA[i] = c >> 3;
        colA[i] = (((c & 7) ^ ((c >> 3) & 7)) << 3);
    }
    int rowB[4], colB[4];
    #pragma unroll
    for (int i = 0; i < 4; ++i) {
        const int c = w * 256 + i * 64 + l;
        rowB[i] = c >> 3;
        colB[i] = (((c & 7) ^ ((c >> 3) & 7)) << 3);
    }

    f32x4 acc[2][4] = {};

    auto STAGE = [&](int d, int k0) {
        #pragma unroll
        for (int i = 0; i < 2; ++i)
            gl2lds16(Ap + (long)(m0 + rowA[i]) * lda + k0 + colA[i],
                     &smA[d][0] + (w * 128 + i * 64) * 8);
        #pragma unroll
        for (int i = 0; i < 4; ++i)
            gl2lds16(Bp + (long)(n0 + rowB[i]) * ldbT + k0 + colB[i],
                     &smB[d][0] + (w * 256 + i * 64) * 8);
    };
    auto COMPUTE = [&](int d) {
        const char* Ab = (const char*)&smA[d][0];
        const char* Bb = (const char*)&smB[d][0];
        #pragma unroll
        for (int ks = 0; ks < 2; ++ks) {
            s16x8 af[2], bf[4];
            #pragma unroll
            for (int i = 0; i < 2; ++i) {
                const int r = wm + i * 16 + lrow;
                af[i] = __builtin_bit_cast(s16x8, *reinterpret_cast<const u16x8*>(
                    Ab + r * 128 + (((ks * 4 + lhi) ^ (r & 7)) << 4)));
            }
            #pragma unroll
            for (int j = 0; j < 4; ++j) {
                const int r = wn + j * 16 + lrow;
                bf[j] = __builtin_bit_cast(s16x8, *reinterpret_cast<const u16x8*>(
                    Bb + r * 128 + (((ks * 4 + lhi) ^ (r & 7)) << 4)));
            }
            #pragma unroll
            for (int i = 0; i < 2; ++i)
                #pragma unroll
                for (int j = 0; j < 4; ++j)
                    acc[i][j] = __builtin_amdgcn_mfma_f32_16x16x32_bf16(af[i], bf[j], acc[i][j], 0, 0, 0);
        }
    };

    STAGE(0, 0);
    __syncthreads();
    int cur = 0;
    for (int k0 = 0; k0 < K; k0 += 64) {
        if (k0 + 64 < K) STAGE(cur ^ 1, k0 + 64);
        COMPUTE(cur);
        __syncthreads();
        cur ^= 1;
    }

    if (EPI == 2) {
        // QKV epilogue: rope for q/k (pairs thread-local), transpose for v
        const int h = (n0 + wn) >> 6;
        unsigned short* qb = qkv_bf;                 // [tok][1024] roped
        unsigned short* kb = qkv_bf + 1048576;       // [tok][1024] roped
        unsigned short* vt = qkv_bf + 2097152;       // [(b*16+h)*64+d][512]
        #pragma unroll
        for (int i = 0; i < 2; ++i) {
            const int r0 = m0 + wm + i * 16 + lhi * 4;
            #pragma unroll
            for (int e = 0; e < 4; ++e) {
                const int r = r0 + e;
                if (wsel == 2) {
                    const int bh = (r >> 9) * NH + h, s = r & 511;
                    #pragma unroll
                    for (int j = 0; j < 4; ++j)
                        vt[((long)(bh * 64 + j * 16 + lrow)) * 512 + s] = f2bf(acc[i][j][e]);
                } else {
                    unsigned short* ob = (wsel == 0) ? qb : kb;
                    const int pos = pid[r];
                    const float c0 = tc[pos * 32 + lrow],      s0 = ts[pos * 32 + lrow];
                    const float c1 = tc[pos * 32 + 16 + lrow], s1 = ts[pos * 32 + 16 + lrow];
                    const float a0 = acc[i][0][e], a1 = acc[i][1][e];
                    const float a2 = acc[i][2][e], a3 = acc[i][3][e];
                    const long rb = (long)r * DIM + (n0 + wn) + lrow;
                    ob[rb]      = f2bf(a0 * c0 - a2 * s0);
                    ob[rb + 16] = f2bf(a1 * c1 - a3 * s1);
                    ob[rb + 32] = f2bf(a2 * c0 + a0 * s0);
                    ob[rb + 48] = f2bf(a3 * c1 + a1 * s1);
                }
            }
        }
        return;
    }

    #pragma unroll
    for (int i = 0; i < 2; ++i) {
        const int r0 = m0 + wm + i * 16 + lhi * 4;
        #pragma unroll
        for (int j = 0; j < 4; ++j) {
            const int c = n0 + wn + j * 16 + lrow;
            #pragma unroll
            for (int e = 0; e < 4; ++e) {
                const int r = r0 + e;
                const long idx = (long)(r >> 9) * rhi + (long)(r & 511) * ldc + c;
                if (EPI == 1) atomicAdd(&Cp[idx], acc[i][j][e]);
                else          Cp[idx] = acc[i][j][e];
            }
        }
    }
}

// ===========================================================================
// Fused gate+up+silu GEMM (r12-validated): 128x64 tiles of g and u, shared A,
// 64 KiB dbuf, epilogue gu_bf = bf16(silu(g)*u). grid (DFF/64, M/128) = 512.
// ===========================================================================
__global__ __launch_bounds__(256)
void gemm_gu(const unsigned short* __restrict__ A,
             const unsigned short* __restrict__ Bg0,
             const unsigned short* __restrict__ Bu0,
             unsigned short* __restrict__ GU, int K, int lda, int ldbT)
{
    __shared__ unsigned short sm[32768];     // 64 KiB
    char* const lds = (char*)sm;

    const int tid = threadIdx.x;
    const int m0  = blockIdx.y * 128;
    const int n0  = blockIdx.x * 64;

    const unsigned short* Bg = Bg0 + (long)n0 * ldbT;
    const unsigned short* Bu = Bu0 + (long)n0 * ldbT;

    const int w = tid >> 6, l = tid & 63;
    const int lrow = l & 15, lhi = l >> 4;
    const int wm = (w >> 1) * 64, wn = (w & 1) * 32;

    int rowA[4], colA[4];
    #pragma unroll
    for (int i = 0; i < 4; ++i) {
        const int c = w * 256 + i * 64 + l;
        rowA[i] = c >> 3;
        colA[i] = (((c & 7) ^ ((c >> 3) & 7)) << 3);
    }
    int rowB[2], colB[2];
    #pragma unroll
    for (int i = 0; i < 2; ++i) {
        const int c = w * 128 + i * 64 + l;
        rowB[i] = c >> 3;
        colB[i] = (((c & 7) ^ ((c >> 3) & 7)) << 3);
    }

    f32x4 accg[4][2] = {};
    f32x4 accu[4][2] = {};

    auto STAGE = [&](int d, int k0) {
        char* Ab  = lds + d * 16384;
        char* Bgb = lds + 32768 + d * 8192;
        char* Bub = lds + 49152 + d * 8192;
        #pragma unroll
        for (int i = 0; i < 4; ++i) {
            const int ub = (w * 256 + i * 64) * 16;
            gl2lds16(A + (long)(m0 + rowA[i]) * lda + k0 + colA[i], Ab + ub);
        }
        #pragma unroll
        for (int i = 0; i < 2; ++i) {
            const int ub = (w * 128 + i * 64) * 16;
            gl2lds16(Bg + (long)rowB[i] * ldbT + k0 + colB[i], Bgb + ub);
            gl2lds16(Bu + (long)rowB[i] * ldbT + k0 + colB[i], Bub + ub);
        }
    };
    auto COMPUTE = [&](int d) {
        const char* Ab  = lds + d * 16384;
        const char* Bgb = lds + 32768 + d * 8192;
        const char* Bub = lds + 49152 + d * 8192;
        #pragma unroll
        for (int ks = 0; ks < 2; ++ks) {
            s16x8 af[4], bg[2], bu[2];
            #pragma unroll
            for (int i = 0; i < 4; ++i) {
                const int r = wm + i * 16 + lrow;
                af[i] = __builtin_bit_cast(s16x8, *reinterpret_cast<const u16x8*>(
                    Ab + r * 128 + (((ks * 4 + lhi) ^ (r & 7)) << 4)));
            }
            #pragma unroll
            for (int j = 0; j < 2; ++j) {
                const int r = wn + j * 16 + lrow;
                const int off = r * 128 + (((ks * 4 + lhi) ^ (r & 7)) << 4);
                bg[j] = __builtin_bit_cast(s16x8, *reinterpret_cast<const u16x8*>(Bgb + off));
                bu[j] = __builtin_bit_cast(s16x8, *reinterpret_cast<const u16x8*>(Bub + off));
            }
            #pragma unroll
            for (int i = 0; i < 4; ++i)
                #pragma unroll
                for (int j = 0; j < 2; ++j) {
                    accg[i][j] = __builtin_amdgcn_mfma_f32_16x16x32_bf16(af[i], bg[j], accg[i][j], 0, 0, 0);
                    accu[i][j] = __builtin_amdgcn_mfma_f32_16x16x32_bf16(af[i], bu[j], accu[i][j], 0, 0, 0);
                }
        }
    };

    STAGE(0, 0);
    __syncthreads();
    int cur = 0;
    for (int k0 = 0; k0 < K; k0 += 64) {
        if (k0 + 64 < K) STAGE(cur ^ 1, k0 + 64);
        COMPUTE(cur);
        __syncthreads();
        cur ^= 1;
    }

    #pragma unroll
    for (int i = 0; i < 4; ++i) {
        const int r0 = m0 + wm + i * 16 + lhi * 4;
        #pragma unroll
        for (int j = 0; j < 2; ++j) {
            const int c = n0 + wn + j * 16 + lrow;
            #pragma unroll
            for (int e = 0; e < 4; ++e) {
                const float gx = accg[i][j][e];
                const float ux = accu[i][j][e];
                const float val = gx / (1.0f + __expf(-gx)) * ux;
                GU[(long)(r0 + e) * DFF + c] = f2bf(val);
            }
        }
    }
}

// transpose + f32->bf16 convert: src f32 [R][Cn] -> dst bf16 [Cn][R]
__global__ __launch_bounds__(256)
void tconv_kernel(const float* __restrict__ src, unsigned short* __restrict__ dst,
                  int R, int Cn, long sS, long sD)
{
    __shared__ float tile[64][65];
    const int c0 = blockIdx.x * 64, r0 = blockIdx.y * 64;
    const float* s = src + (long)blockIdx.z * sS;
    unsigned short* d = dst + (long)blockIdx.z * sD;
    const int tid = threadIdx.x;
    #pragma unroll
    for (int it = 0; it < 4; ++it) {
        const int idx = tid + it * 256;
        const int r = idx >> 4, c4 = (idx & 15) * 4;
        f32x4 v = *reinterpret_cast<const f32x4*>(&s[(long)(r0 + r) * Cn + c0 + c4]);
        tile[r][c4] = v[0]; tile[r][c4+1] = v[1]; tile[r][c4+2] = v[2]; tile[r][c4+3] = v[3];
    }
    __syncthreads();
    #pragma unroll
    for (int it = 0; it < 4; ++it) {
        const int idx = tid + it * 256;
        const int n = idx >> 4, r4 = (idx & 15) * 4;
        u16x4 o = { f2bf(tile[r4][n]), f2bf(tile[r4+1][n]),
                    f2bf(tile[r4+2][n]), f2bf(tile[r4+3][n]) };
        *reinterpret_cast<u16x4*>(&d[(long)(c0 + n) * R + r0 + r4]) = o;
    }
}

// rope tables: tc/ts[pos][i], pos<512, i<32
__global__ __launch_bounds__(256)
void ropetab_kernel(float* __restrict__ tc, float* __restrict__ ts)
{
    const int idx = blockIdx.x * 256 + threadIdx.x;   // 16384
    const int pos = idx >> 5, i = idx & 31;
    const float invf = powf(10000.0f, -(float)i * (1.0f / 32.0f));
    const float ang = (float)pos * invf;
    tc[idx] = cosf(ang);
    ts[idx] = sinf(ang);
}

// concat [fused_input2 | primary_hidden] -> bf16 xcat[1024][2048]
__global__ __launch_bounds__(256)
void concat_bf_kernel(const float* __restrict__ a, const float* __restrict__ b,
                      unsigned short* __restrict__ out)
{
    const long i = ((long)blockIdx.x * 256 + threadIdx.x) * 4;
    const int row = (int)(i >> 11), col = (int)(i & 2047);
    const float* src = (col < DIM) ? &a[(long)row * DIM + col]
                                   : &b[(long)row * DIM + col - DIM];
    f32x4 v = *reinterpret_cast<const f32x4*>(src);
    u16x4 o = { f2bf(v[0]), f2bf(v[1]), f2bf(v[2]), f2bf(v[3]) };
    *reinterpret_cast<u16x4*>(out + i) = o;
}

// RMSNorm f32 in -> bf16 out, one block per row of 1024
__global__ __launch_bounds__(256)
void rms_bf_kernel(const float* __restrict__ in, const float* __restrict__ w,
                   unsigned short* __restrict__ out)
{
    __shared__ float red[4];
    const int row = blockIdx.x, tid = threadIdx.x;
    const long base = (long)row * DIM + tid * 4;
    f32x4 v = *reinterpret_cast<const f32x4*>(&in[base]);
    float ss = v[0]*v[0] + v[1]*v[1] + v[2]*v[2] + v[3]*v[3];
    for (int off = 32; off; off >>= 1) ss += __shfl_down(ss, off);
    if ((tid & 63) == 0) red[tid >> 6] = ss;
    __syncthreads();
    float s = red[0] + red[1] + red[2] + red[3];
    float r = 1.0f / sqrtf(s * (1.0f / DIM) + 1e-5f);
    f32x4 wv = *reinterpret_cast<const f32x4*>(&w[tid * 4]);
    u16x4 ob = { f2bf(v[0]*r*wv[0]), f2bf(v[1]*r*wv[1]),
                 f2bf(v[2]*r*wv[2]), f2bf(v[3]*r*wv[3]) };
    *reinterpret_cast<u16x4*>(out + base) = ob;
}

// Flash attention on pre-roped bf16 q/k and pre-transposed bf16 vT.
// QBLK=64, 256 thr / 4 waves, K/V double-buffered via global_load_lds with
// XOR pre-swizzled source. grid (8 qtiles, 32 bh).
__global__ __launch_bounds__(256)
void attn_bf(const unsigned short* __restrict__ qb,
             const unsigned short* __restrict__ kb,
             const unsigned short* __restrict__ vt,
             unsigned short* __restrict__ attv)
{
    __shared__ unsigned short Qs[4096];        // 64x64 swizzled
    __shared__ unsigned short Ps[64][72];
    __shared__ unsigned short Ks[2][4096];
    __shared__ unsigned short Vs[2][4096];
    const int tid = threadIdx.x;
    const int qt = blockIdx.x, bh = blockIdx.y, b = bh >> 4, h = bh & 15;
    const int q0 = qt * 64;
    const int w = tid >> 6, l = tid & 63, lrow = l & 15, lhi = l >> 4;

    int rowS[2], colS[2];
    #pragma unroll
    for (int i = 0; i < 2; ++i) {
        const int c = w * 128 + i * 64 + l;
        rowS[i] = c >> 3;
        colS[i] = (((c & 7) ^ ((c >> 3) & 7)) << 3);   // u16 elems
    }

    auto STAGE64 = [&](const unsigned short* src, long rstride, unsigned short* dst) {
        #pragma unroll
        for (int i = 0; i < 2; ++i)
            gl2lds16(src + (long)rowS[i] * rstride + colS[i],
                     dst + (w * 128 + i * 64) * 8);
    };

    STAGE64(qb + (long)(b * SEQ + q0) * DIM + h * HD, DIM, Qs);

    auto STAGE_KV = [&](int kt, int d) {
        const int t0 = kt * 64;
        STAGE64(kb + (long)(b * SEQ + t0) * DIM + h * HD, DIM, Ks[d]);
        STAGE64(vt + (long)(bh * 64) * 512 + t0, 512, Vs[d]);
    };

    float m_run[4], l_run[4];
    f32x4 o[4] = {};
    #pragma unroll
    for (int j = 0; j < 4; ++j) { m_run[j] = -1e30f; l_run[j] = 0.f; }
    const float scale = 0.125f;

    STAGE_KV(0, 0);
    __syncthreads();

    for (int kt = 0; kt <= qt; ++kt) {
        const int cur = kt & 1;
        const int t0 = kt * 64;
        if (kt < qt) STAGE_KV(kt + 1, cur ^ 1);   // prefetch under compute

        f32x4 s[4] = {};
        __builtin_amdgcn_s_setprio(1);
        #pragma unroll
        for (int ks = 0; ks < 2; ++ks) {
            const int rq = w * 16 + lrow;
            s16x8 aq = __builtin_bit_cast(s16x8, *reinterpret_cast<const u16x8*>(
                (const char*)Qs + rq * 128 + (((ks * 4 + lhi) ^ (rq & 7)) << 4)));
            #pragma unroll
            for (int j = 0; j < 4; ++j) {
                const int rk = j * 16 + lrow;
                s16x8 bk = __builtin_bit_cast(s16x8, *reinterpret_cast<const u16x8*>(
                    (const char*)Ks[cur] + rk * 128 + (((ks * 4 + lhi) ^ (rk & 7)) << 4)));
                s[j] = __builtin_amdgcn_mfma_f32_16x16x32_bf16(aq, bk, s[j], 0, 0, 0);
            }
        }
        __builtin_amdgcn_s_setprio(0);

        float pv[4][4], corr[4];
        #pragma unroll
        for (int j = 0; j < 4; ++j) {
            const int qrow = q0 + w * 16 + lhi * 4 + j;
            float sv[4], mx = -1e30f;
            #pragma unroll
            for (int tcq = 0; tcq < 4; ++tcq) {
                const int tcur = t0 + tcq * 16 + lrow;
                float vvv = s[tcq][j] * scale;
                if (tcur > qrow) vvv = -1e30f;
                sv[tcq] = vvv;
                mx = fmaxf(mx, vvv);
            }
            #pragma unroll
            for (int mk = 1; mk < 16; mk <<= 1) mx = fmaxf(mx, __shfl_xor(mx, mk));
            const float mnew = fmaxf(m_run[j], mx);
            const float c = __expf(m_run[j] - mnew);
            m_run[j] = mnew;
            float rs = 0.f;
            #pragma unroll
            for (int tcq = 0; tcq < 4; ++tcq) {
                float p = __expf(sv[tcq] - mnew);
                pv[tcq][j] = p;
                rs += p;
            }
            #pragma unroll
            for (int mk = 1; mk < 16; mk <<= 1) rs += __shfl_xor(rs, mk);
            l_run[j] = l_run[j] * c + rs;
            corr[j] = c;
        }

        #pragma unroll
        for (int tcq = 0; tcq < 4; ++tcq)
            #pragma unroll
            for (int j = 0; j < 4; ++j)
                Ps[w * 16 + lhi * 4 + j][tcq * 16 + lrow] = f2bf(pv[tcq][j]);

        #pragma unroll
        for (int dn = 0; dn < 4; ++dn)
            #pragma unroll
            for (int j = 0; j < 4; ++j)
                o[dn][j] *= corr[j];
        __builtin_amdgcn_s_setprio(1);
        #pragma unroll
        for (int ks = 0; ks < 2; ++ks) {
            s16x8 ap = __builtin_bit_cast(s16x8,
                *reinterpret_cast<const u16x8*>(&Ps[w * 16 + lrow][ks * 32 + lhi * 8]));
            #pragma unroll
            for (int dn = 0; dn < 4; ++dn) {
                const int rv = dn * 16 + lrow;
                s16x8 bv = __builtin_bit_cast(s16x8, *reinterpret_cast<const u16x8*>(
                    (const char*)Vs[cur] + rv * 128 + (((ks * 4 + lhi) ^ (rv & 7)) << 4)));
                o[dn] = __builtin_amdgcn_mfma_f32_16x16x32_bf16(ap, bv, o[dn], 0, 0, 0);
            }
        }
        __builtin_amdgcn_s_setprio(0);
        __syncthreads();
    }

    #pragma unroll
    for (int dn = 0; dn < 4; ++dn)
        #pragma unroll
        for (int j = 0; j < 4; ++j) {
            const int qrow = q0 + w * 16 + lhi * 4 + j;
            const int d = dn * 16 + lrow;
            const long idx = (((long)(b * SEQ + qrow)) * NH + h) * HD + d;
            attv[idx] = f2bf(o[dn][j] / l_run[j]);
        }
}

// ---------------------------------------------------------------------------
extern "C" void kernel_launch(void* const* d_in, const int* in_sizes, int n_in,
                              void* d_out, int out_size, void* d_ws, size_t ws_size,
                              hipStream_t stream)
{
    const float* f2   = (const float*)d_in[0];
    const float* ph   = (const float*)d_in[1];
    const float* wbr  = (const float*)d_in[3];
    const float* ln1  = (const float*)d_in[4];
    const float* wq   = (const float*)d_in[5];
    const float* wk   = (const float*)d_in[6];
    const float* wv   = (const float*)d_in[7];
    const float* wo   = (const float*)d_in[8];
    const float* ln2  = (const float*)d_in[9];
    const float* wg   = (const float*)d_in[10];
    const float* wu   = (const float*)d_in[11];
    const float* wd   = (const float*)d_in[12];
    const float* nw   = (const float*)d_in[13];
    const float* wout = (const float*)d_in[14];
    const int*   pid  = (const int*)d_in[15];
    float* out = (float*)d_out;

    const long M1 = 1048576;
    dim3 blk(256);

    float* ws = (float*)d_ws;
    float* h    = ws;                        // 1M f32
    float* tcos = ws + 1 * M1;               // 16384 f32
    float* tsin = ws + 1 * M1 + 16384;
    unsigned short* xcat_bf = (unsigned short*)(ws + 2 * M1);   // 2M u16
    unsigned short* x_bf    = (unsigned short*)(ws + 3 * M1);   // 1M u16
    unsigned short* att_bf  = (unsigned short*)(ws + 3 * M1 + 524288);
    unsigned short* gu_bf   = (unsigned short*)(ws + 4 * M1);   // 4M u16
    unsigned short* qkv_bf  = (unsigned short*)(ws + 6 * M1);   // 3M u16 (q,k,vT)
    unsigned short* wT      = (unsigned short*)(ws + 17 * M1);
    unsigned short* wbrT  = wT;                  // 2M elts
    unsigned short* wqT   = wbrT + 2 * M1;       // 12M
    unsigned short* wkT   = wqT + 12 * M1;
    unsigned short* wvT   = wkT + 12 * M1;
    unsigned short* woT   = wvT + 12 * M1;
    unsigned short* wgT   = woT + 12 * M1;       // 48M
    unsigned short* wuT   = wgT + 48 * M1;
    unsigned short* wdT   = wuT + 48 * M1;
    unsigned short* woutT = wdT + 48 * M1;       // 14.34M

    // prepass: rope tables + weight convert/transpose (~1.25 GB at HBM BW)
    ropetab_kernel<<<64, blk, 0, stream>>>(tcos, tsin);
    tconv_kernel<<<dim3(16, 32, 1), blk, 0, stream>>>(wbr, wbrT, 2048, 1024, 0, 0);
    tconv_kernel<<<dim3(16, 16, NL), blk, 0, stream>>>(wq, wqT, 1024, 1024, M1, M1);
    tconv_kernel<<<dim3(16, 16, NL), blk, 0, stream>>>(wk, wkT, 1024, 1024, M1, M1);
    tconv_kernel<<<dim3(16, 16, NL), blk, 0, stream>>>(wv, wvT, 1024, 1024, M1, M1);
    tconv_kernel<<<dim3(16, 16, NL), blk, 0, stream>>>(wo, woT, 1024, 1024, M1, M1);
    tconv_kernel<<<dim3(64, 16, NL), blk, 0, stream>>>(wg, wgT, 1024, 4096, 4 * M1, 4 * M1);
    tconv_kernel<<<dim3(64, 16, NL), blk, 0, stream>>>(wu, wuT, 1024, 4096, 4 * M1, 4 * M1);
    tconv_kernel<<<dim3(16, 64, NL), blk, 0, stream>>>(wd, wdT, 4096, 1024, 4 * M1, 4 * M1);
    tconv_kernel<<<dim3(32, 16, CHD), blk, 0, stream>>>(wout, woutT, 1024, 2048, 2 * M1, 2 * M1);

    concat_bf_kernel<<<2048, blk, 0, stream>>>(f2, ph, xcat_bf);
    hipMemsetAsync(h, 0, M1 * 4, stream);
    // bridge: 64x128 tiles, K=2048 split 4 -> 512 blocks (8 K-steps each)
    gemm64<1><<<dim3(8, 16, 4), blk, 0, stream>>>(
        xcat_bf, wbrT, wbrT, wbrT, h, 512, 2048, 2048, 1024,
        512 * 1024, 0, 512, 4, nullptr, nullptr, nullptr, nullptr);

    for (int i = 0; i < NL; ++i) {
        rms_bf_kernel<<<1024, blk, 0, stream>>>(h, ln1 + (long)i * DIM, x_bf);
        // QKV: 64x128 tiles -> 384 blocks, fused rope/V-transpose epilogue
        gemm64<2><<<dim3(8, 16, 3), blk, 0, stream>>>(
            x_bf, wqT + (long)i * M1, wkT + (long)i * M1, wvT + (long)i * M1,
            nullptr, 1024, 1024, 1024, 1024, 0, 0, 0, 1,
            tcos, tsin, pid, qkv_bf);
        attn_bf<<<dim3(8, 32), blk, 0, stream>>>(
            qkv_bf, qkv_bf + M1, qkv_bf + 2 * M1, att_bf);
        // wo: 64x128 tiles, K=1024 split 4 -> 512 blocks, atomic into live h
        gemm64<1><<<dim3(8, 16, 4), blk, 0, stream>>>(
            att_bf, woT + (long)i * M1, woT + (long)i * M1, woT + (long)i * M1, h,
            256, 1024, 1024, 1024, 512 * 1024, 0, 256, 4,
            nullptr, nullptr, nullptr, nullptr);

        rms_bf_kernel<<<1024, blk, 0, stream>>>(h, ln2 + (long)i * DIM, x_bf);
        // fused gate+up+silu: 128x64 tiles, 512 blocks
        gemm_gu<<<dim3(64, 8), blk, 0, stream>>>(
            x_bf, wgT + (long)i * 4 * M1, wuT + (long)i * 4 * M1, gu_bf, 1024, 1024, 1024);
        // down: 64x128 tiles, K=4096 split 4 -> 512 blocks, K=1024/block
        gemm64<1><<<dim3(8, 16, 4), blk, 0, stream>>>(
            gu_bf, wdT + (long)i * 4 * M1, wdT + (long)i * 4 * M1, wdT + (long)i * 4 * M1, h,
            1024, 4096, 4096, 1024, 512 * 1024, 0, 1024, 4,
            nullptr, nullptr, nullptr, nullptr);
    }

    rms_bf_kernel<<<1024, blk, 0, stream>>>(h, nw, x_bf);
    // head: 128x128 tiles, strided-B (7 heads) -> grid (16,8,7) = 896 blocks
    gemm_bf<0><<<dim3(16, 8, CHD), blk, 0, stream>>>(
        x_bf, woutT, nullptr, nullptr, out,
        1024, 1024, 1024, 2048, CHD * 512 * 2048, 2 * M1, (long)512 * 2048, 0, 1);
}